// Round 6
// baseline (190.317 us; speedup 1.0000x reference)
//
#include <hip/hip_runtime.h>

typedef __attribute__((ext_vector_type(8))) short bf16x8;
typedef __attribute__((ext_vector_type(4))) float f32x4;
typedef __attribute__((ext_vector_type(8))) unsigned short u16x8;
typedef unsigned int u32;
typedef unsigned short u16;

#define CIN 512
#define CO  512
#define HH  64
#define WW  64
#define BB  8
#define HP  66
#define WPAD 68
#define HPW (HP*WPAD)
#define KK  4608  // CIN*9

#define SIG_BYTES  (BB*CO*4)                       // 16384
#define WMOD_ELEMS ((size_t)BB*9*64*CO*8)          // 18,874,368
#define WMOD_BYTES (WMOD_ELEMS*2)                  // 37,748,736
#define IMGT_ELEMS ((size_t)BB*64*HP*WPAD*8)       // 18,382,848  [b][grp64][66][68][8]
#define IMGT_BYTES (IMGT_ELEMS*2)                  // 36,765,696
#define WS_NEED    ((size_t)SIG_BYTES + WMOD_BYTES + IMGT_BYTES)

__device__ __forceinline__ u16 f2bf(float f) {
  union { float f; u32 u; } v; v.f = f;
  u32 r = (v.u + 0x7FFFu + ((v.u >> 16) & 1u)) >> 16;  // RNE
  return (u16)r;
}

// ---------------- K1: sigma[b][o] = rsqrt(sum_i,t (w*(s+1))^2 + eps) ----------
__global__ void k_sigma(const float* __restrict__ weight, const float* __restrict__ s,
                        float* __restrict__ sigma) {
  int o = blockIdx.x;          // 512 blocks
  int tid = threadIdx.x;       // 256 threads
  const float* wrow = weight + (size_t)o * KK;
  float acc[BB];
#pragma unroll
  for (int b = 0; b < BB; ++b) acc[b] = 0.f;
  for (int e = tid; e < KK; e += 256) {
    float w = wrow[e];
    float w2 = w * w;
    int i = e / 9;
#pragma unroll
    for (int b = 0; b < BB; ++b) {
      float m = s[b * CIN + i] + 1.0f;
      acc[b] += w2 * m * m;
    }
  }
#pragma unroll
  for (int b = 0; b < BB; ++b) {
#pragma unroll
    for (int off = 32; off >= 1; off >>= 1)
      acc[b] += __shfl_down(acc[b], off);
  }
  __shared__ float red[4][BB];
  int wv = tid >> 6, ln = tid & 63;
  if (ln == 0) {
#pragma unroll
    for (int b = 0; b < BB; ++b) red[wv][b] = acc[b];
  }
  __syncthreads();
  if (tid < BB) {
    float t = red[0][tid] + red[1][tid] + red[2][tid] + red[3][tid];
    sigma[tid * CO + o] = rsqrtf(t + 1e-8f);
  }
}

// ------------- K2: wmod[b][t][kg][o][8] bf16, LDS-staged coalesced ------------
__global__ __launch_bounds__(256) void k_wmod(const float* __restrict__ weight,
                                              const float* __restrict__ s,
                                              const float* __restrict__ sigma,
                                              u16* __restrict__ wmod) {
  __shared__ float lw[16][577];
  int bid = blockIdx.x;        // 256 = 32 oc * 8 ic
  int oc = bid & 31, ic = bid >> 5;
  int o0 = oc * 16;
  int tid = threadIdx.x;
  const float* wsrc = weight + (size_t)o0 * KK + ic * 576;
#pragma unroll
  for (int k = 0; k < 9; ++k) {
    int f4 = tid + k * 256;            // 0..2303
    int row = f4 / 144;                // 144 float4 per row
    int col = f4 - row * 144;
    float4 v = *(const float4*)(wsrc + (size_t)row * KK + col * 4);
    lw[row][col*4+0]=v.x; lw[row][col*4+1]=v.y; lw[row][col*4+2]=v.z; lw[row][col*4+3]=v.w;
  }
  __syncthreads();
  int o_l = tid & 15, kg_l = (tid >> 4) & 7;
#pragma unroll
  for (int k = 0; k < 36; ++k) {
    int bt = k * 2 + (tid >> 7);       // 0..71
    int b = bt / 9;
    int t = bt - b * 9;
    int o = o0 + o_l;
    float sig = sigma[b * CO + o];
    u16x8 ov;
#pragma unroll
    for (int j = 0; j < 8; ++j) {
      int il = kg_l * 8 + j;
      float w = lw[o_l][il * 9 + t];
      float m = s[b * CIN + ic * 64 + il] + 1.0f;
      ov[j] = f2bf(w * m * sig);
    }
    *(u16x8*)(wmod + ((size_t)(bt * 64 + (ic * 8 + kg_l)) * CO + o) * 8) = ov;
  }
}

// ------------- K3a: zero pad border of imgt [b][grp][66][68][8] --------------
__global__ void k_pad(u16* __restrict__ imgt) {
  int gid = blockIdx.x * 256 + threadIdx.x;   // 528*256 = 135168 vec-stores
  int grp = gid & 63;
  int pos = gid >> 6;                         // 0..2111 = 8b * 264
  int b = pos / 264;
  int pr = pos - b * 264;
  int yp, xp;
  if (pr < 136) { yp = (pr < 68) ? 0 : 65; xp = (pr < 68) ? pr : pr - 68; }
  else { int q = pr - 136; yp = 1 + (q >> 1); xp = (q & 1) ? 67 : 0; }
  u16x8 z = {0,0,0,0,0,0,0,0};
  *(u16x8*)(imgt + (((size_t)(b * 64 + grp) * HP + yp) * WPAD + xp) * 8) = z;
}

// ------------- K3b: imgt[b][grp(64)][yp(66)][xp(68)][8ch] bf16, interior ------
__global__ void k_imgt(const float* __restrict__ img, u16* __restrict__ imgt) {
  int bid = blockIdx.x;        // 8*64*2*8 = 8192 blocks
  int ic = bid & 7;  int r = bid >> 3;
  int xc = r & 1;    r >>= 1;
  int y  = r & 63;   int b = r >> 6;
  int tid = threadIdx.x;
  __shared__ float lt[64][33];
  {
    int ii = tid >> 2, xq = tid & 3;
    const float* src = img + (((size_t)(b * CIN + ic * 64 + ii)) * HH + y) * WW + xc * 32 + xq * 8;
    float4 v0 = *(const float4*)src;
    float4 v1 = *(const float4*)(src + 4);
    int xb = xq * 8;
    lt[ii][xb+0]=v0.x; lt[ii][xb+1]=v0.y; lt[ii][xb+2]=v0.z; lt[ii][xb+3]=v0.w;
    lt[ii][xb+4]=v1.x; lt[ii][xb+5]=v1.y; lt[ii][xb+6]=v1.z; lt[ii][xb+7]=v1.w;
  }
  __syncthreads();
  int xl = tid >> 3, iq = tid & 7;
  u16x8 ov;
#pragma unroll
  for (int j = 0; j < 8; ++j) ov[j] = f2bf(lt[iq*8+j][xl]);
  size_t dst = (((size_t)(b * 64 + ic * 8 + iq) * HP + (y + 1)) * WPAD + (xc * 32 + xl + 1)) * 8;
  *(u16x8*)(imgt + dst) = ov;
}

// ------- K4: implicit-GEMM conv: 4-wave blocks, 4 blocks/CU, 2-tap groups -----
__device__ __forceinline__ void async16(const u16* g, void* lds) {
  __builtin_amdgcn_global_load_lds((const __attribute__((address_space(1))) u32*)g,
                                   (__attribute__((address_space(3))) u32*)lds, 16, 0, 0);
}

__global__ __launch_bounds__(256, 4) void k_conv(const u16* __restrict__ wmod,
                                                 const u16* __restrict__ imgt,
                                                 float* __restrict__ out) {
  __shared__ alignas(16) u16 abuf[2][2][4096];   // dbuf x 2 taps x 8KB = 32KB
  int bid0 = blockIdx.x;                          // 1024 = 8b * 4ot * 32pt
  int bid  = (bid0 & 7) * 128 + (bid0 >> 3);      // XCD-chunked: each XCD = one b
  int b  = bid >> 7;
  int rem = bid & 127;
  int ot = rem >> 5;                              // 0..3
  int pt = rem & 31;                              // 0..31
  int y0 = pt * 2, obase = ot * 128;
  int tid = threadIdx.x;                          // 256
  int wave = tid >> 6, lane = tid & 63;
  int wm = wave >> 1, wn = wave & 1;              // 2 o-halves x 2 y-rows
  int col0 = lane & 15, kg = lane >> 4;

  // A-stage source: thread covers chunks tid (kg4=tid>>7) and tid+256 (kg4+2)
  const u16* awsrc0 = wmod + (((size_t)(b * 576 + (tid >> 7))) * 512 + obase + (tid & 127)) * 8;
  const u16* awsrc1 = awsrc0 + 2 * 512 * 8;

  // B base: imgt[(b*64+kg)][y0+wn][col0][8]; +icc advances 4 grp rows
  const u16* pB = imgt + (((size_t)(b * 64 + kg) * HP + (y0 + wn)) * WPAD + col0) * 8;

  f32x4 zero = {0.f, 0.f, 0.f, 0.f};
  f32x4 acc[4][4];
#pragma unroll
  for (int i = 0; i < 4; ++i)
#pragma unroll
    for (int j = 0; j < 4; ++j) acc[i][j] = zero;

  bf16x8 B0[4], B1[4];

#define STAGE1(slot, cc, iccv, tv) do { \
  int aoff_ = ((tv) * 64 + (iccv) * 4) * 4096; \
  async16(awsrc0 + aoff_, (void*)(&abuf[slot][cc][0] + (size_t)tid * 8)); \
  async16(awsrc1 + aoff_, (void*)(&abuf[slot][cc][0] + (size_t)(tid + 256) * 8)); \
} while (0)

#define BPF(dst, iccv, tv) do { \
  int ky_ = ((tv) >= 6) ? 2 : (((tv) >= 3) ? 1 : 0); \
  int kx_ = (tv) - 3 * ky_; \
  const u16* pb_ = pB + (size_t)(iccv) * (4 * HPW * 8); \
  dst[0] = *(const bf16x8*)(pb_ + (ky_ * WPAD +  0 + kx_) * 8); \
  dst[1] = *(const bf16x8*)(pb_ + (ky_ * WPAD + 16 + kx_) * 8); \
  dst[2] = *(const bf16x8*)(pb_ + (ky_ * WPAD + 32 + kx_) * 8); \
  dst[3] = *(const bf16x8*)(pb_ + (ky_ * WPAD + 48 + kx_) * 8); \
} while (0)

#define COMPUTE(slot, cc, BR) do { \
  const u16* ab_ = &abuf[slot][cc][(kg * 128 + wm * 64 + col0) * 8]; \
  bf16x8 a_[4]; \
  _Pragma("unroll") \
  for (int am = 0; am < 4; ++am) a_[am] = *(const bf16x8*)(ab_ + am * 128); \
  __builtin_amdgcn_s_setprio(1); \
  _Pragma("unroll") \
  for (int am = 0; am < 4; ++am) { \
    acc[am][0] = __builtin_amdgcn_mfma_f32_16x16x32_bf16(a_[am], BR[0], acc[am][0], 0, 0, 0); \
    acc[am][1] = __builtin_amdgcn_mfma_f32_16x16x32_bf16(a_[am], BR[1], acc[am][1], 0, 0, 0); \
    acc[am][2] = __builtin_amdgcn_mfma_f32_16x16x32_bf16(a_[am], BR[2], acc[am][2], 0, 0, 0); \
    acc[am][3] = __builtin_amdgcn_mfma_f32_16x16x32_bf16(a_[am], BR[3], acc[am][3], 0, 0, 0); \
  } \
  __builtin_amdgcn_s_setprio(0); \
} while (0)

  // prologue: stage taps 0,1 into slot 0; prefetch B(tap 0)
  STAGE1(0, 0, 0, 0);
  STAGE1(0, 1, 0, 1);
  BPF(B0, 0, 0);
  asm volatile("s_waitcnt vmcnt(4)" ::: "memory");   // 4 stage loads done
  __builtin_amdgcn_s_barrier();
  __builtin_amdgcn_sched_barrier(0);

  // 144 taps = 72 groups of 2; track (icc,t) of the group's first tap
  int i0 = 0, t0 = 0;
  for (int gg = 0; gg < 72; ++gg) {
    int slot = gg & 1, ns = slot ^ 1;
    // taps: A=2gg (i0,t0), B=+1, C=+2 (next grp c0), D=+3 (next grp c1)
    int tB = t0 + 1, iB = i0; if (tB >= 9) { tB -= 9; ++iB; }
    int tC = tB + 1, iC = iB; if (tC >= 9) { tC -= 9; ++iC; }
    int tD = tC + 1, iD = iC; if (tD >= 9) { tD -= 9; ++iD; }

    if (gg < 71) { STAGE1(ns, 0, iC, tC); STAGE1(ns, 1, iD, tD); }
    BPF(B1, iB, tB);
    COMPUTE(slot, 0, B0);
    if (gg < 71) BPF(B0, iC, tC);
    COMPUTE(slot, 1, B1);
    if (gg < 71) {
      asm volatile("s_waitcnt vmcnt(8)" ::: "memory");  // oldest 4 (stage) done
      __builtin_amdgcn_s_barrier();
      __builtin_amdgcn_sched_barrier(0);
    }
    t0 = tC; i0 = iC;
  }
#undef COMPUTE
#undef BPF
#undef STAGE1

  int y = y0 + wn;
#pragma unroll
  for (int am = 0; am < 4; ++am) {
    int o = obase + wm * 64 + am * 16 + kg * 4;     // row = (lane>>4)*4 + reg
#pragma unroll
    for (int an = 0; an < 4; ++an) {
      int x = an * 16 + col0;                        // col = lane&15
      float* op = out + (((size_t)(b * CO + o)) * HH + y) * WW + x;
#pragma unroll
      for (int rg = 0; rg < 4; ++rg)
        op[(size_t)rg * HH * WW] = acc[am][an][rg];
    }
  }
}

// ---------------- Fallback (ws too small): naive but correct ------------------
__global__ void k_naive(const float* __restrict__ img, const float* __restrict__ s,
                        const float* __restrict__ weight, const float* __restrict__ sigma,
                        float* __restrict__ out) {
  int bid = blockIdx.x;          // 8*512*64, 64 threads
  int y = bid & 63; int r = bid >> 6; int o = r & 511; int b = r >> 9;
  int x = threadIdx.x;
  float sig = sigma[b * CO + o];
  float acc = 0.f;
  for (int i = 0; i < CIN; ++i) {
    float m = s[b * CIN + i] + 1.0f;
    const float* wp = weight + ((size_t)o * CIN + i) * 9;
    const float* ip = img + ((size_t)(b * CIN + i)) * HH * WW;
#pragma unroll
    for (int ky = 0; ky < 3; ++ky) {
      int yy = y + ky - 1;
      if (yy < 0 || yy > 63) continue;
#pragma unroll
      for (int kx = 0; kx < 3; ++kx) {
        int xx = x + kx - 1;
        float iv = (xx >= 0 && xx < 64) ? ip[yy * 64 + xx] : 0.f;
        acc += wp[ky * 3 + kx] * m * iv;
      }
    }
  }
  out[((size_t)(b * CO + o) * HH + y) * WW + x] = acc * sig;
}

extern "C" void kernel_launch(void* const* d_in, const int* in_sizes, int n_in,
                              void* d_out, int out_size, void* d_ws, size_t ws_size,
                              hipStream_t stream) {
  const float* img    = (const float*)d_in[0];
  const float* s      = (const float*)d_in[1];
  const float* weight = (const float*)d_in[2];
  float* out = (float*)d_out;
  char* ws = (char*)d_ws;
  float* sigma = (float*)ws;

  if (ws_size >= WS_NEED) {
    u16* wmod = (u16*)(ws + SIG_BYTES);
    u16* imgt = (u16*)(ws + SIG_BYTES + WMOD_BYTES);
    k_sigma<<<512, 256, 0, stream>>>(weight, s, sigma);
    k_wmod<<<256, 256, 0, stream>>>(weight, s, sigma, wmod);
    k_pad<<<528, 256, 0, stream>>>(imgt);
    k_imgt<<<8192, 256, 0, stream>>>(img, imgt);
    k_conv<<<1024, 256, 0, stream>>>(wmod, imgt, out);
  } else {
    k_sigma<<<512, 256, 0, stream>>>(weight, s, sigma);
    k_naive<<<BB * CO * HH, 64, 0, stream>>>(img, s, weight, sigma, out);
  }
}